// Round 1
// baseline (275.519 us; speedup 1.0000x reference)
//
#include <hip/hip_runtime.h>

// Problem constants (from reference setup_inputs):
//   B=4, H=4, S=8, N=32768, W=32 -> P=W^3=32768, C=128, F=C/H=32
#define P_W3 32768
#define F_DIM 32
#define S_DIM 8
#define N_DIM 32768
#define BH_DIM 16   // B*H
#define C_DIM 128

// ---------------------------------------------------------------------------
// Kernel 1: transpose conv [B, C, P] -> T [B, H, P, F]
// so that the F=32 features of one gather index are contiguous (128 B).
// Channel offset identity: b*C + h*F == (b*H+h)*F == bh*F.
// ---------------------------------------------------------------------------
__global__ __launch_bounds__(256) void transpose_kernel(
    const float* __restrict__ conv, float* __restrict__ T) {
    const int PT = P_W3 / 64;                 // 512 p-tiles per bh
    const int bh = blockIdx.x / PT;
    const int p0 = (blockIdx.x % PT) * 64;

    __shared__ float tile[F_DIM][65];         // +1 pad: conflict-free both phases

    const float* src = conv + (size_t)bh * F_DIM * P_W3;
    const int pp = threadIdx.x & 63;
    const int f0 = threadIdx.x >> 6;          // 0..3
#pragma unroll
    for (int k = 0; k < 8; ++k) {
        const int f = f0 + k * 4;
        tile[f][pp] = src[(size_t)f * P_W3 + p0 + pp];   // coalesced over p
    }
    __syncthreads();

    float* dst = T + (size_t)bh * P_W3 * F_DIM;
    const int f  = threadIdx.x & 31;
    const int pq = threadIdx.x >> 5;          // 0..7
#pragma unroll
    for (int k = 0; k < 8; ++k) {
        const int p = pq + k * 8;
        dst[(size_t)(p0 + p) * F_DIM + f] = tile[f][p];  // coalesced over f,p
    }
}

// ---------------------------------------------------------------------------
// Kernel 2: gather + weighted combine from transposed layout.
// One thread per (bh, n); accumulates all F=32 features in registers.
// Each gather is 8 float4 loads from one contiguous 128 B chunk.
// ---------------------------------------------------------------------------
__global__ __launch_bounds__(256) void gather_t_kernel(
    const float* __restrict__ lc, const int* __restrict__ idx,
    const float* __restrict__ T, float* __restrict__ out) {
    const int t  = blockIdx.x * 256 + threadIdx.x;
    const int n  = t & (N_DIM - 1);
    const int bh = t >> 15;                   // N_DIM = 2^15

    const float* Tb = T + (size_t)bh * P_W3 * F_DIM;
    const int*   ip = idx + (size_t)bh * S_DIM * N_DIM + n;
    const float* wp = lc  + (size_t)bh * S_DIM * N_DIM + n;

    float acc[F_DIM];
#pragma unroll
    for (int f = 0; f < F_DIM; ++f) acc[f] = 0.f;

#pragma unroll
    for (int s = 0; s < S_DIM; ++s) {
        const int   id = ip[(size_t)s * N_DIM];   // coalesced over n
        const float w  = wp[(size_t)s * N_DIM];   // coalesced over n
        const float4* src = (const float4*)(Tb + (size_t)id * F_DIM);
#pragma unroll
        for (int j = 0; j < 8; ++j) {
            const float4 v = src[j];
            acc[4 * j + 0] += w * v.x;
            acc[4 * j + 1] += w * v.y;
            acc[4 * j + 2] += w * v.z;
            acc[4 * j + 3] += w * v.w;
        }
    }

    float* op = out + (size_t)bh * F_DIM * N_DIM + n;
#pragma unroll
    for (int f = 0; f < F_DIM; ++f)
        op[(size_t)f * N_DIM] = acc[f];           // coalesced over n
}

// ---------------------------------------------------------------------------
// Fallback (only if ws too small): gather directly from [B,C,P] layout.
// ---------------------------------------------------------------------------
__global__ __launch_bounds__(256) void gather_direct_kernel(
    const float* __restrict__ lc, const int* __restrict__ idx,
    const float* __restrict__ conv, float* __restrict__ out) {
    const int t  = blockIdx.x * 256 + threadIdx.x;
    const int n  = t & (N_DIM - 1);
    const int bh = t >> 15;

    const float* Cb = conv + (size_t)bh * F_DIM * P_W3;
    const int*   ip = idx + (size_t)bh * S_DIM * N_DIM + n;
    const float* wp = lc  + (size_t)bh * S_DIM * N_DIM + n;

    float acc[F_DIM];
#pragma unroll
    for (int f = 0; f < F_DIM; ++f) acc[f] = 0.f;

#pragma unroll
    for (int s = 0; s < S_DIM; ++s) {
        const int   id = ip[(size_t)s * N_DIM];
        const float w  = wp[(size_t)s * N_DIM];
#pragma unroll
        for (int f = 0; f < F_DIM; ++f)
            acc[f] += w * Cb[(size_t)f * P_W3 + id];
    }

    float* op = out + (size_t)bh * F_DIM * N_DIM + n;
#pragma unroll
    for (int f = 0; f < F_DIM; ++f)
        op[(size_t)f * N_DIM] = acc[f];
}

extern "C" void kernel_launch(void* const* d_in, const int* in_sizes, int n_in,
                              void* d_out, int out_size, void* d_ws, size_t ws_size,
                              hipStream_t stream) {
    const float* lc   = (const float*)d_in[0];   // [B,H,S,N] fp32
    const int*   idx  = (const int*)d_in[1];     // [B,H,S,N] int32
    const float* conv = (const float*)d_in[2];   // [B,C,W,W,W] fp32
    float*       out  = (float*)d_out;           // [B,C,N] fp32

    const size_t need = (size_t)BH_DIM * P_W3 * F_DIM * sizeof(float);  // 64 MiB
    if (ws_size >= need) {
        float* T = (float*)d_ws;
        transpose_kernel<<<BH_DIM * (P_W3 / 64), 256, 0, stream>>>(conv, T);
        gather_t_kernel<<<(BH_DIM * N_DIM) / 256, 256, 0, stream>>>(lc, idx, T, out);
    } else {
        gather_direct_kernel<<<(BH_DIM * N_DIM) / 256, 256, 0, stream>>>(lc, idx, conv, out);
    }
}

// Round 2
// 201.703 us; speedup vs baseline: 1.3660x; 1.3660x over previous
//
#include <hip/hip_runtime.h>

// Problem constants (from reference setup_inputs):
//   B=4, H=4, S=8, N=32768, W=32 -> P=W^3=32768, C=128, F=C/H=32
#define P_W3 32768
#define F_DIM 32
#define S_DIM 8
#define N_DIM 32768
#define BH_DIM 16   // B*H

// ---------------------------------------------------------------------------
// Kernel 1: transpose conv [bh, f, p] -> T [bh, p, f]  (all 16B accesses)
// so the F=32 features of one gather index are one contiguous 128 B chunk.
// ---------------------------------------------------------------------------
__global__ __launch_bounds__(256) void transpose_kernel(
    const float* __restrict__ conv, float* __restrict__ T) {
    const int PT = P_W3 / 64;                 // 512 p-tiles per bh
    const int bh = blockIdx.x / PT;
    const int p0 = (blockIdx.x % PT) * 64;

    __shared__ float tile[F_DIM][68];         // row = 272 B (16B-aligned, padded)

    const float* src = conv + (size_t)bh * F_DIM * P_W3 + p0;
    {
        const int pp = (threadIdx.x & 15) * 4;
        const int f  = threadIdx.x >> 4;      // 0..15
#pragma unroll
        for (int k = 0; k < 2; ++k) {
            const float4 v = *(const float4*)(src + (size_t)(f + 16 * k) * P_W3 + pp);
            tile[f + 16 * k][pp + 0] = v.x;
            tile[f + 16 * k][pp + 1] = v.y;
            tile[f + 16 * k][pp + 2] = v.z;
            tile[f + 16 * k][pp + 3] = v.w;
        }
    }
    __syncthreads();

    float* dst = T + ((size_t)bh * P_W3 + p0) * F_DIM;
    {
        const int f4 = (threadIdx.x & 7) * 4;
        const int p  = threadIdx.x >> 3;      // 0..31
#pragma unroll
        for (int k = 0; k < 2; ++k) {
            float4 v;
            v.x = tile[f4 + 0][p + 32 * k];
            v.y = tile[f4 + 1][p + 32 * k];
            v.z = tile[f4 + 2][p + 32 * k];
            v.w = tile[f4 + 3][p + 32 * k];
            *(float4*)(dst + (size_t)(p + 32 * k) * F_DIM + f4) = v;   // 128B/8 lanes
        }
    }
}

// ---------------------------------------------------------------------------
// Kernel 2: wave-cooperative gather. 8 lanes per (s,n) gather: lane sub loads
// float4 at T[id*32 + sub*4] -> one 128B coalesced transaction per gather
// instead of 8 scattered 16B transactions. Block = 256 threads = 32 n values.
// ---------------------------------------------------------------------------
__global__ __launch_bounds__(256) void gather_t_kernel(
    const float* __restrict__ lc, const int* __restrict__ idx,
    const float* __restrict__ T, float* __restrict__ out) {
    const int NB  = N_DIM / 32;               // 1024 n-blocks per bh
    const int bh  = blockIdx.x / NB;
    const int nb  = (blockIdx.x % NB) * 32;
    const int t   = threadIdx.x;
    const int wv  = t >> 6;                   // wave in block: 0..3
    const int ln  = t & 63;
    const int g   = ln >> 3;                  // which of the wave's 8 n: 0..7
    const int sub = ln & 7;                   // which 16B of the 128B chunk
    const int n   = nb + wv * 8 + g;

    const float* Tb = T + (size_t)bh * P_W3 * F_DIM + sub * 4;
    const int*   ip = idx + (size_t)bh * S_DIM * N_DIM + n;
    const float* wp = lc  + (size_t)bh * S_DIM * N_DIM + n;

    float4 acc = {0.f, 0.f, 0.f, 0.f};
#pragma unroll
    for (int s = 0; s < S_DIM; ++s) {
        const int   id = ip[(size_t)s * N_DIM];   // 8 distinct vals, 1 line/wave
        const float w  = wp[(size_t)s * N_DIM];
        const float4 v = *(const float4*)(Tb + (size_t)id * F_DIM);
        acc.x += w * v.x;
        acc.y += w * v.y;
        acc.z += w * v.z;
        acc.w += w * v.w;
    }

    // LDS transpose so stores are fully coalesced over n.
    __shared__ float smem[32][36];            // [n_local][f], row 144B (16B-aligned)
    *(float4*)&smem[wv * 8 + g][sub * 4] = acc;
    __syncthreads();

    const int f = t >> 3;                     // 0..31
    const int c = t & 7;                      // n_local quad: 0..7
    float4 o;
    o.x = smem[c * 4 + 0][f];
    o.y = smem[c * 4 + 1][f];
    o.z = smem[c * 4 + 2][f];
    o.w = smem[c * 4 + 3][f];
    *(float4*)(out + ((size_t)bh * F_DIM + f) * N_DIM + nb + c * 4) = o;
}

// ---------------------------------------------------------------------------
// Fallback (only if ws too small): gather directly from [B,C,P] layout.
// ---------------------------------------------------------------------------
__global__ __launch_bounds__(256) void gather_direct_kernel(
    const float* __restrict__ lc, const int* __restrict__ idx,
    const float* __restrict__ conv, float* __restrict__ out) {
    const int t  = blockIdx.x * 256 + threadIdx.x;
    const int n  = t & (N_DIM - 1);
    const int bh = t >> 15;

    const float* Cb = conv + (size_t)bh * F_DIM * P_W3;
    const int*   ip = idx + (size_t)bh * S_DIM * N_DIM + n;
    const float* wp = lc  + (size_t)bh * S_DIM * N_DIM + n;

    float acc[F_DIM];
#pragma unroll
    for (int f = 0; f < F_DIM; ++f) acc[f] = 0.f;

#pragma unroll
    for (int s = 0; s < S_DIM; ++s) {
        const int   id = ip[(size_t)s * N_DIM];
        const float w  = wp[(size_t)s * N_DIM];
#pragma unroll
        for (int f = 0; f < F_DIM; ++f)
            acc[f] += w * Cb[(size_t)f * P_W3 + id];
    }

    float* op = out + (size_t)bh * F_DIM * N_DIM + n;
#pragma unroll
    for (int f = 0; f < F_DIM; ++f)
        op[(size_t)f * N_DIM] = acc[f];
}

extern "C" void kernel_launch(void* const* d_in, const int* in_sizes, int n_in,
                              void* d_out, int out_size, void* d_ws, size_t ws_size,
                              hipStream_t stream) {
    const float* lc   = (const float*)d_in[0];   // [B,H,S,N] fp32
    const int*   idx  = (const int*)d_in[1];     // [B,H,S,N] int32
    const float* conv = (const float*)d_in[2];   // [B,C,W,W,W] fp32
    float*       out  = (float*)d_out;           // [B,C,N] fp32

    const size_t need = (size_t)BH_DIM * P_W3 * F_DIM * sizeof(float);  // 64 MiB
    if (ws_size >= need) {
        float* T = (float*)d_ws;
        transpose_kernel<<<BH_DIM * (P_W3 / 64), 256, 0, stream>>>(conv, T);
        gather_t_kernel<<<BH_DIM * (N_DIM / 32), 256, 0, stream>>>(lc, idx, T, out);
    } else {
        gather_direct_kernel<<<(BH_DIM * N_DIM) / 256, 256, 0, stream>>>(lc, idx, conv, out);
    }
}

// Round 4
// 180.747 us; speedup vs baseline: 1.5243x; 1.1159x over previous
//
#include <hip/hip_runtime.h>

// Problem constants (from reference setup_inputs):
//   B=4, H=4, S=8, N=32768, W=32 -> P=W^3=32768, C=128, F=C/H=32
#define P_W3 32768
#define F_DIM 32
#define S_DIM 8
#define N_DIM 32768
#define BH_DIM 16   // B*H

typedef _Float16 half8 __attribute__((ext_vector_type(8)));  // 16 B
typedef float    f32x4 __attribute__((ext_vector_type(4)));  // 16 B, clang-native

// ---------------------------------------------------------------------------
// Kernel 1: transpose + convert conv [bh, f, p] fp32 -> T [bh, p, f] fp16.
// One gather target becomes a contiguous 64 B chunk. conv loads nontemporal
// (streamed once) so they don't evict T from L3.
// ---------------------------------------------------------------------------
__global__ __launch_bounds__(256) void transpose_f16_kernel(
    const float* __restrict__ conv, _Float16* __restrict__ T) {
    const int PT = P_W3 / 64;                 // 512 p-tiles per bh
    const int bh = blockIdx.x / PT;
    const int p0 = (blockIdx.x % PT) * 64;

    __shared__ float tile[F_DIM][65];         // stride 65: 2-way max on readout

    const float* src = conv + (size_t)bh * F_DIM * P_W3 + p0;
    {
        const int pp = (threadIdx.x & 15) * 4;
        const int f  = threadIdx.x >> 4;      // 0..15
#pragma unroll
        for (int k = 0; k < 2; ++k) {
            const f32x4 v = __builtin_nontemporal_load(
                (const f32x4*)(src + (size_t)(f + 16 * k) * P_W3 + pp));
            tile[f + 16 * k][pp + 0] = v.x;
            tile[f + 16 * k][pp + 1] = v.y;
            tile[f + 16 * k][pp + 2] = v.z;
            tile[f + 16 * k][pp + 3] = v.w;
        }
    }
    __syncthreads();

    _Float16* dst = T + ((size_t)bh * P_W3 + p0) * F_DIM;
    {
        const int f0 = (threadIdx.x & 3) * 8;
        const int p  = threadIdx.x >> 2;      // 0..63
        half8 hv;
#pragma unroll
        for (int j = 0; j < 8; ++j) hv[j] = (_Float16)tile[f0 + j][p];
        *(half8*)(dst + (size_t)p * F_DIM + f0) = hv;   // 64B/4 lanes contiguous
    }
}

// ---------------------------------------------------------------------------
// Kernel 2: wave-cooperative fp16 gather. 4 lanes per (s,n); lane q loads the
// 16 B sub-chunk of the 64 B feature row T[id*32 + q*8 .. +7]. A wave covers
// 16 gathers per instruction, fully coalesced per gather. fp32 accumulate.
// idx/lc loads and out stores are nontemporal to keep T resident in L3.
// ---------------------------------------------------------------------------
__global__ __launch_bounds__(256) void gather_f16_kernel(
    const float* __restrict__ lc, const int* __restrict__ idx,
    const _Float16* __restrict__ T, float* __restrict__ out) {
    const int NB = N_DIM / 64;                // 512 n-blocks per bh
    const int bh = blockIdx.x / NB;
    const int nb = (blockIdx.x % NB) * 64;
    const int t  = threadIdx.x;
    const int q  = t & 3;                     // 16B sub-chunk 0..3
    const int nl = t >> 2;                    // local n 0..63
    const int n  = nb + nl;

    const _Float16* Tb = T + (size_t)bh * P_W3 * F_DIM + q * 8;
    const int*   ip = idx + (size_t)bh * S_DIM * N_DIM + n;
    const float* wp = lc  + (size_t)bh * S_DIM * N_DIM + n;

    float acc[8];
#pragma unroll
    for (int j = 0; j < 8; ++j) acc[j] = 0.f;

#pragma unroll
    for (int s = 0; s < S_DIM; ++s) {
        const int   id = __builtin_nontemporal_load(ip + (size_t)s * N_DIM);
        const float w  = __builtin_nontemporal_load(wp + (size_t)s * N_DIM);
        const half8 v  = *(const half8*)(Tb + (size_t)id * F_DIM);
#pragma unroll
        for (int j = 0; j < 8; ++j) acc[j] += w * (float)v[j];
    }

    // LDS transpose so out stores are coalesced 128B segments over n.
    __shared__ float smem[64][33];
#pragma unroll
    for (int j = 0; j < 8; ++j) smem[nl][q * 8 + j] = acc[j];
    __syncthreads();

    const int f  = t >> 3;                    // 0..31
    const int c0 = t & 7;
#pragma unroll
    for (int k = 0; k < 2; ++k) {
        const int c = c0 + 8 * k;             // n quad 0..15
        f32x4 o;
        o.x = smem[c * 4 + 0][f];
        o.y = smem[c * 4 + 1][f];
        o.z = smem[c * 4 + 2][f];
        o.w = smem[c * 4 + 3][f];
        __builtin_nontemporal_store(
            o, (f32x4*)(out + ((size_t)bh * F_DIM + f) * N_DIM + nb + c * 4));
    }
}

// ---------------------------------------------------------------------------
// Fallback (only if ws too small): gather directly from [B,C,P] layout.
// ---------------------------------------------------------------------------
__global__ __launch_bounds__(256) void gather_direct_kernel(
    const float* __restrict__ lc, const int* __restrict__ idx,
    const float* __restrict__ conv, float* __restrict__ out) {
    const int t  = blockIdx.x * 256 + threadIdx.x;
    const int n  = t & (N_DIM - 1);
    const int bh = t >> 15;

    const float* Cb = conv + (size_t)bh * F_DIM * P_W3;
    const int*   ip = idx + (size_t)bh * S_DIM * N_DIM + n;
    const float* wp = lc  + (size_t)bh * S_DIM * N_DIM + n;

    float acc[F_DIM];
#pragma unroll
    for (int f = 0; f < F_DIM; ++f) acc[f] = 0.f;

#pragma unroll
    for (int s = 0; s < S_DIM; ++s) {
        const int   id = ip[(size_t)s * N_DIM];
        const float w  = wp[(size_t)s * N_DIM];
#pragma unroll
        for (int f = 0; f < F_DIM; ++f)
            acc[f] += w * Cb[(size_t)f * P_W3 + id];
    }

    float* op = out + (size_t)bh * F_DIM * N_DIM + n;
#pragma unroll
    for (int f = 0; f < F_DIM; ++f)
        op[(size_t)f * N_DIM] = acc[f];
}

extern "C" void kernel_launch(void* const* d_in, const int* in_sizes, int n_in,
                              void* d_out, int out_size, void* d_ws, size_t ws_size,
                              hipStream_t stream) {
    const float* lc   = (const float*)d_in[0];   // [B,H,S,N] fp32
    const int*   idx  = (const int*)d_in[1];     // [B,H,S,N] int32
    const float* conv = (const float*)d_in[2];   // [B,C,W,W,W] fp32
    float*       out  = (float*)d_out;           // [B,C,N] fp32

    const size_t need = (size_t)BH_DIM * P_W3 * F_DIM * sizeof(_Float16);  // 32 MiB
    if (ws_size >= need) {
        _Float16* T = (_Float16*)d_ws;
        transpose_f16_kernel<<<BH_DIM * (P_W3 / 64), 256, 0, stream>>>(conv, T);
        gather_f16_kernel<<<BH_DIM * (N_DIM / 64), 256, 0, stream>>>(lc, idx, T, out);
    } else {
        gather_direct_kernel<<<(BH_DIM * N_DIM) / 256, 256, 0, stream>>>(lc, idx, conv, out);
    }
}